// Round 1
// baseline (3797.521 us; speedup 1.0000x reference)
//
#include <hip/hip_runtime.h>

#define E_TOTAL 1000000
#define EMB     128
#define NRBF    16
#define NATOMS  50000

__device__ __forceinline__ float silu_f(float v) {
    return v * (1.0f / (1.0f + __expf(-v)));
}

// ---------------------------------------------------------------------------
// Edge kernel: per edge e
//   h = silu(x[e] @ Wx + bx)           (K=128)
//   g = silu((ca*rbf[e]) @ Wr + br)    (K=16)
//   conv = (cb*g) * (cx*h)
//   acc[idnb[e]] += conv               (atomic segment-sum)
// Tile: 64 edges per block-iteration; thread tile 4 edges x 8 cols.
// X in LDS (stride 132 words: bank-conflict-free quad reads), W from global
// (L1/L2-hot 64KB; 16 lanes share each address -> coalesced broadcast).
// ---------------------------------------------------------------------------
__global__ __launch_bounds__(256, 2)
void edge_kernel(const float* __restrict__ x,
                 const float* __restrict__ rbf,
                 const int*   __restrict__ idnb,
                 const float* __restrict__ Wx,
                 const float* __restrict__ bx,
                 const float* __restrict__ Wr,
                 const float* __restrict__ br,
                 const float* __restrict__ c_a,
                 const float* __restrict__ c_b,
                 const float* __restrict__ c_x,
                 float* __restrict__ acc)
{
    __shared__ float sX[64][132];   // 33.8 KB, +4 pad words -> conflict-free
    __shared__ float sR[64][20];    // 5 KB
    __shared__ int   sIdx[64];

    const int tid = threadIdx.x;
    const int tx  = tid & 15;       // 16 col groups of 8
    const int ty  = tid >> 4;       // 16 edge groups of 4
    const int j0  = tx * 8;
    const int e0  = ty * 4;

    const float ca = c_a[0];
    const float sc = c_b[0] * c_x[0];

    float bxr[8], brr[8];
#pragma unroll
    for (int c = 0; c < 8; ++c) { bxr[c] = bx[j0 + c]; brr[c] = br[j0 + c]; }

    const int ntiles = E_TOTAL / 64;   // 15625, exact (no tail)
    for (int tile = blockIdx.x; tile < ntiles; tile += gridDim.x) {
        const size_t base = (size_t)tile * 64;
        __syncthreads();   // protect LDS from previous iteration's readers
#pragma unroll
        for (int i = 0; i < 8; ++i) {
            const int f = tid + i * 256;      // 0..2047 float4 slots
            const int e = f >> 5, seg = f & 31;
            const float4 v = *(const float4*)(x + (base + e) * EMB + seg * 4);
            *(float4*)&sX[e][seg * 4] = v;
        }
        {
            const int e = tid >> 2, seg = tid & 3;
            const float4 v = *(const float4*)(rbf + (base + e) * NRBF + seg * 4);
            *(float4*)&sR[e][seg * 4] = v;
        }
        if (tid < 64) sIdx[tid] = idnb[base + tid];
        __syncthreads();

        float hacc[4][8];
        float gacc[4][8];
#pragma unroll
        for (int i = 0; i < 4; ++i)
#pragma unroll
            for (int c = 0; c < 8; ++c) { hacc[i][c] = 0.f; gacc[i][c] = 0.f; }

        // ---- g accumulation: K = 16 ----
#pragma unroll
        for (int kq = 0; kq < NRBF / 4; ++kq) {
            const int k = kq * 4;
            float xa[4][4];
#pragma unroll
            for (int i = 0; i < 4; ++i) {
                const float4 v = *(const float4*)&sR[e0 + i][k];
                xa[i][0] = v.x; xa[i][1] = v.y; xa[i][2] = v.z; xa[i][3] = v.w;
            }
#pragma unroll
            for (int kk = 0; kk < 4; ++kk) {
                const float4 w0 = *(const float4*)(Wr + (size_t)(k + kk) * EMB + j0);
                const float4 w1 = *(const float4*)(Wr + (size_t)(k + kk) * EMB + j0 + 4);
                const float wv[8] = {w0.x, w0.y, w0.z, w0.w, w1.x, w1.y, w1.z, w1.w};
#pragma unroll
                for (int i = 0; i < 4; ++i) {
                    const float xv = xa[i][kk];
#pragma unroll
                    for (int c = 0; c < 8; ++c)
                        gacc[i][c] = __builtin_fmaf(xv, wv[c], gacc[i][c]);
                }
            }
        }

        // ---- h accumulation: K = 128 ----
#pragma unroll 2
        for (int kq = 0; kq < EMB / 4; ++kq) {
            const int k = kq * 4;
            float xa[4][4];
#pragma unroll
            for (int i = 0; i < 4; ++i) {
                const float4 v = *(const float4*)&sX[e0 + i][k];
                xa[i][0] = v.x; xa[i][1] = v.y; xa[i][2] = v.z; xa[i][3] = v.w;
            }
#pragma unroll
            for (int kk = 0; kk < 4; ++kk) {
                const float4 w0 = *(const float4*)(Wx + (size_t)(k + kk) * EMB + j0);
                const float4 w1 = *(const float4*)(Wx + (size_t)(k + kk) * EMB + j0 + 4);
                const float wv[8] = {w0.x, w0.y, w0.z, w0.w, w1.x, w1.y, w1.z, w1.w};
#pragma unroll
                for (int i = 0; i < 4; ++i) {
                    const float xv = xa[i][kk];
#pragma unroll
                    for (int c = 0; c < 8; ++c)
                        hacc[i][c] = __builtin_fmaf(xv, wv[c], hacc[i][c]);
                }
            }
        }

        // ---- gate + scatter-add ----
#pragma unroll
        for (int i = 0; i < 4; ++i) {
            const int aidx = sIdx[e0 + i];
            float* dst = acc + (size_t)aidx * EMB + j0;
#pragma unroll
            for (int c = 0; c < 8; ++c) {
                const float h = silu_f(hacc[i][c] + bxr[c]);
                const float g = silu_f(__builtin_fmaf(gacc[i][c], ca, brr[c]));
                unsafeAtomicAdd(dst + c, sc * g * h);
            }
        }
    }
}

// ---------------------------------------------------------------------------
// Atom MLP layer: Y = silu(X @ W + b), M rows (tail-guarded), 128x128 weights.
// Same tiling as edge kernel.
// ---------------------------------------------------------------------------
__global__ __launch_bounds__(256, 2)
void layer_kernel(const float* __restrict__ X,
                  const float* __restrict__ W,
                  const float* __restrict__ b,
                  float* __restrict__ Y,
                  int M)
{
    __shared__ float sX[64][132];

    const int tid = threadIdx.x;
    const int tx  = tid & 15;
    const int ty  = tid >> 4;
    const int j0  = tx * 8;
    const int e0  = ty * 4;

    float brr[8];
#pragma unroll
    for (int c = 0; c < 8; ++c) brr[c] = b[j0 + c];

    const int base = blockIdx.x * 64;
#pragma unroll
    for (int i = 0; i < 8; ++i) {
        const int f = tid + i * 256;
        const int e = f >> 5, seg = f & 31;
        const int row = base + e;
        float4 v = make_float4(0.f, 0.f, 0.f, 0.f);
        if (row < M) v = *(const float4*)(X + (size_t)row * EMB + seg * 4);
        *(float4*)&sX[e][seg * 4] = v;
    }
    __syncthreads();

    float acc[4][8];
#pragma unroll
    for (int i = 0; i < 4; ++i)
#pragma unroll
        for (int c = 0; c < 8; ++c) acc[i][c] = 0.f;

#pragma unroll 2
    for (int kq = 0; kq < EMB / 4; ++kq) {
        const int k = kq * 4;
        float xa[4][4];
#pragma unroll
        for (int i = 0; i < 4; ++i) {
            const float4 v = *(const float4*)&sX[e0 + i][k];
            xa[i][0] = v.x; xa[i][1] = v.y; xa[i][2] = v.z; xa[i][3] = v.w;
        }
#pragma unroll
        for (int kk = 0; kk < 4; ++kk) {
            const float4 w0 = *(const float4*)(W + (size_t)(k + kk) * EMB + j0);
            const float4 w1 = *(const float4*)(W + (size_t)(k + kk) * EMB + j0 + 4);
            const float wv[8] = {w0.x, w0.y, w0.z, w0.w, w1.x, w1.y, w1.z, w1.w};
#pragma unroll
            for (int i = 0; i < 4; ++i) {
                const float xv = xa[i][kk];
#pragma unroll
                for (int c = 0; c < 8; ++c)
                    acc[i][c] = __builtin_fmaf(xv, wv[c], acc[i][c]);
            }
        }
    }

#pragma unroll
    for (int i = 0; i < 4; ++i) {
        const int row = base + e0 + i;
        if (row < M) {
            float o[8];
#pragma unroll
            for (int c = 0; c < 8; ++c) o[c] = silu_f(acc[i][c] + brr[c]);
            float4 v0 = make_float4(o[0], o[1], o[2], o[3]);
            float4 v1 = make_float4(o[4], o[5], o[6], o[7]);
            *(float4*)(Y + (size_t)row * EMB + j0)     = v0;
            *(float4*)(Y + (size_t)row * EMB + j0 + 4) = v1;
        }
    }
}

// ---------------------------------------------------------------------------
// Final projection: out[i] = dot(A[i], Wf) * cf
// ---------------------------------------------------------------------------
__global__ __launch_bounds__(256)
void final_kernel(const float* __restrict__ A,
                  const float* __restrict__ Wf,
                  const float* __restrict__ cf,
                  float* __restrict__ out)
{
    const int i = blockIdx.x * blockDim.x + threadIdx.x;
    if (i >= NATOMS) return;
    const float4* row = (const float4*)(A + (size_t)i * EMB);
    const float4* w   = (const float4*)Wf;
    float acc = 0.f;
#pragma unroll
    for (int k = 0; k < EMB / 4; ++k) {
        const float4 a = row[k];
        const float4 b = w[k];
        acc = __builtin_fmaf(a.x, b.x, acc);
        acc = __builtin_fmaf(a.y, b.y, acc);
        acc = __builtin_fmaf(a.z, b.z, acc);
        acc = __builtin_fmaf(a.w, b.w, acc);
    }
    out[i] = acc * cf[0];
}

extern "C" void kernel_launch(void* const* d_in, const int* in_sizes, int n_in,
                              void* d_out, int out_size, void* d_ws, size_t ws_size,
                              hipStream_t stream) {
    const float* x    = (const float*)d_in[0];
    const float* rbf  = (const float*)d_in[1];
    const int*   idnb = (const int*)  d_in[2];
    // d_in[3] = n_atoms (fixed 50000)
    const float* Wx   = (const float*)d_in[4];
    const float* bx   = (const float*)d_in[5];
    const float* Wr   = (const float*)d_in[6];
    const float* brf  = (const float*)d_in[7];
    const float* W1   = (const float*)d_in[8];
    const float* b1   = (const float*)d_in[9];
    const float* W2   = (const float*)d_in[10];
    const float* b2   = (const float*)d_in[11];
    const float* W3   = (const float*)d_in[12];
    const float* b3   = (const float*)d_in[13];
    const float* Wf   = (const float*)d_in[14];
    const float* c_a  = (const float*)d_in[15];
    const float* c_b  = (const float*)d_in[16];
    const float* c_x  = (const float*)d_in[17];
    const float* c_f  = (const float*)d_in[18];

    float* out = (float*)d_out;
    float* acc = (float*)d_ws;                       // [NATOMS][128]
    float* buf = acc + (size_t)NATOMS * EMB;         // [NATOMS][128]

    // accumulator must be zero every call (ws is poisoned once, not restored)
    hipMemsetAsync(acc, 0, (size_t)NATOMS * EMB * sizeof(float), stream);

    edge_kernel<<<1024, 256, 0, stream>>>(x, rbf, idnb, Wx, bx, Wr, brf,
                                          c_a, c_b, c_x, acc);

    const int atiles = (NATOMS + 63) / 64;           // 782
    layer_kernel<<<atiles, 256, 0, stream>>>(acc, W1, b1, buf, NATOMS);
    layer_kernel<<<atiles, 256, 0, stream>>>(buf, W2, b2, acc, NATOMS);
    layer_kernel<<<atiles, 256, 0, stream>>>(acc, W3, b3, buf, NATOMS);

    final_kernel<<<(NATOMS + 255) / 256, 256, 0, stream>>>(buf, Wf, c_f, out);
}

// Round 2
// 3796.941 us; speedup vs baseline: 1.0002x; 1.0002x over previous
//
#include <hip/hip_runtime.h>

#define E_TOTAL 1000000
#define EMB     128
#define NRBF    16
#define NATOMS  50000

__device__ __forceinline__ float silu_f(float v) {
    return v * (1.0f / (1.0f + __expf(-v)));
}

// ---------------------------------------------------------------------------
// Edge kernel: per edge e
//   h = silu(x[e] @ Wx + bx)           (K=128)
//   g = silu((ca*rbf[e]) @ Wr + br)    (K=16)
//   conv = (cb*g) * (cx*h)
//   acc[idnb[e]] += conv               (atomic segment-sum)
// Tile: 64 edges per block-iteration; thread tile 4 edges x 8 cols.
// X in LDS (stride 132 words: bank-conflict-free quad reads), W from global
// (L1/L2-hot 64KB; 16 lanes share each address -> coalesced broadcast).
// ---------------------------------------------------------------------------
__global__ __launch_bounds__(256, 2)
void edge_kernel(const float* __restrict__ x,
                 const float* __restrict__ rbf,
                 const int*   __restrict__ idnb,
                 const float* __restrict__ Wx,
                 const float* __restrict__ bx,
                 const float* __restrict__ Wr,
                 const float* __restrict__ br,
                 const float* __restrict__ c_a,
                 const float* __restrict__ c_b,
                 const float* __restrict__ c_x,
                 float* __restrict__ acc)
{
    __shared__ float sX[64][132];   // 33.8 KB, +4 pad words -> conflict-free
    __shared__ float sR[64][20];    // 5 KB
    __shared__ int   sIdx[64];

    const int tid = threadIdx.x;
    const int tx  = tid & 15;       // 16 col groups of 8
    const int ty  = tid >> 4;       // 16 edge groups of 4
    const int j0  = tx * 8;
    const int e0  = ty * 4;

    const float ca = c_a[0];
    const float sc = c_b[0] * c_x[0];

    float bxr[8], brr[8];
#pragma unroll
    for (int c = 0; c < 8; ++c) { bxr[c] = bx[j0 + c]; brr[c] = br[j0 + c]; }

    const int ntiles = E_TOTAL / 64;   // 15625, exact (no tail)
    for (int tile = blockIdx.x; tile < ntiles; tile += gridDim.x) {
        const size_t base = (size_t)tile * 64;
        __syncthreads();   // protect LDS from previous iteration's readers
#pragma unroll
        for (int i = 0; i < 8; ++i) {
            const int f = tid + i * 256;      // 0..2047 float4 slots
            const int e = f >> 5, seg = f & 31;
            const float4 v = *(const float4*)(x + (base + e) * EMB + seg * 4);
            *(float4*)&sX[e][seg * 4] = v;
        }
        {
            const int e = tid >> 2, seg = tid & 3;
            const float4 v = *(const float4*)(rbf + (base + e) * NRBF + seg * 4);
            *(float4*)&sR[e][seg * 4] = v;
        }
        if (tid < 64) sIdx[tid] = idnb[base + tid];
        __syncthreads();

        float hacc[4][8];
        float gacc[4][8];
#pragma unroll
        for (int i = 0; i < 4; ++i)
#pragma unroll
            for (int c = 0; c < 8; ++c) { hacc[i][c] = 0.f; gacc[i][c] = 0.f; }

        // ---- g accumulation: K = 16 ----
#pragma unroll
        for (int kq = 0; kq < NRBF / 4; ++kq) {
            const int k = kq * 4;
            float xa[4][4];
#pragma unroll
            for (int i = 0; i < 4; ++i) {
                const float4 v = *(const float4*)&sR[e0 + i][k];
                xa[i][0] = v.x; xa[i][1] = v.y; xa[i][2] = v.z; xa[i][3] = v.w;
            }
#pragma unroll
            for (int kk = 0; kk < 4; ++kk) {
                const float4 w0 = *(const float4*)(Wr + (size_t)(k + kk) * EMB + j0);
                const float4 w1 = *(const float4*)(Wr + (size_t)(k + kk) * EMB + j0 + 4);
                const float wv[8] = {w0.x, w0.y, w0.z, w0.w, w1.x, w1.y, w1.z, w1.w};
#pragma unroll
                for (int i = 0; i < 4; ++i) {
                    const float xv = xa[i][kk];
#pragma unroll
                    for (int c = 0; c < 8; ++c)
                        gacc[i][c] = __builtin_fmaf(xv, wv[c], gacc[i][c]);
                }
            }
        }

        // ---- h accumulation: K = 128 ----
#pragma unroll 2
        for (int kq = 0; kq < EMB / 4; ++kq) {
            const int k = kq * 4;
            float xa[4][4];
#pragma unroll
            for (int i = 0; i < 4; ++i) {
                const float4 v = *(const float4*)&sX[e0 + i][k];
                xa[i][0] = v.x; xa[i][1] = v.y; xa[i][2] = v.z; xa[i][3] = v.w;
            }
#pragma unroll
            for (int kk = 0; kk < 4; ++kk) {
                const float4 w0 = *(const float4*)(Wx + (size_t)(k + kk) * EMB + j0);
                const float4 w1 = *(const float4*)(Wx + (size_t)(k + kk) * EMB + j0 + 4);
                const float wv[8] = {w0.x, w0.y, w0.z, w0.w, w1.x, w1.y, w1.z, w1.w};
#pragma unroll
                for (int i = 0; i < 4; ++i) {
                    const float xv = xa[i][kk];
#pragma unroll
                    for (int c = 0; c < 8; ++c)
                        hacc[i][c] = __builtin_fmaf(xv, wv[c], hacc[i][c]);
                }
            }
        }

        // ---- gate + scatter-add ----
#pragma unroll
        for (int i = 0; i < 4; ++i) {
            const int aidx = sIdx[e0 + i];
            float* dst = acc + (size_t)aidx * EMB + j0;
#pragma unroll
            for (int c = 0; c < 8; ++c) {
                const float h = silu_f(hacc[i][c] + bxr[c]);
                const float g = silu_f(__builtin_fmaf(gacc[i][c], ca, brr[c]));
                unsafeAtomicAdd(dst + c, sc * g * h);
            }
        }
    }
}

// ---------------------------------------------------------------------------
// Atom MLP layer: Y = silu(X @ W + b), M rows (tail-guarded), 128x128 weights.
// Same tiling as edge kernel.
// ---------------------------------------------------------------------------
__global__ __launch_bounds__(256, 2)
void layer_kernel(const float* __restrict__ X,
                  const float* __restrict__ W,
                  const float* __restrict__ b,
                  float* __restrict__ Y,
                  int M)
{
    __shared__ float sX[64][132];

    const int tid = threadIdx.x;
    const int tx  = tid & 15;
    const int ty  = tid >> 4;
    const int j0  = tx * 8;
    const int e0  = ty * 4;

    float brr[8];
#pragma unroll
    for (int c = 0; c < 8; ++c) brr[c] = b[j0 + c];

    const int base = blockIdx.x * 64;
#pragma unroll
    for (int i = 0; i < 8; ++i) {
        const int f = tid + i * 256;
        const int e = f >> 5, seg = f & 31;
        const int row = base + e;
        float4 v = make_float4(0.f, 0.f, 0.f, 0.f);
        if (row < M) v = *(const float4*)(X + (size_t)row * EMB + seg * 4);
        *(float4*)&sX[e][seg * 4] = v;
    }
    __syncthreads();

    float acc[4][8];
#pragma unroll
    for (int i = 0; i < 4; ++i)
#pragma unroll
        for (int c = 0; c < 8; ++c) acc[i][c] = 0.f;

#pragma unroll 2
    for (int kq = 0; kq < EMB / 4; ++kq) {
        const int k = kq * 4;
        float xa[4][4];
#pragma unroll
        for (int i = 0; i < 4; ++i) {
            const float4 v = *(const float4*)&sX[e0 + i][k];
            xa[i][0] = v.x; xa[i][1] = v.y; xa[i][2] = v.z; xa[i][3] = v.w;
        }
#pragma unroll
        for (int kk = 0; kk < 4; ++kk) {
            const float4 w0 = *(const float4*)(W + (size_t)(k + kk) * EMB + j0);
            const float4 w1 = *(const float4*)(W + (size_t)(k + kk) * EMB + j0 + 4);
            const float wv[8] = {w0.x, w0.y, w0.z, w0.w, w1.x, w1.y, w1.z, w1.w};
#pragma unroll
            for (int i = 0; i < 4; ++i) {
                const float xv = xa[i][kk];
#pragma unroll
                for (int c = 0; c < 8; ++c)
                    acc[i][c] = __builtin_fmaf(xv, wv[c], acc[i][c]);
            }
        }
    }

#pragma unroll
    for (int i = 0; i < 4; ++i) {
        const int row = base + e0 + i;
        if (row < M) {
            float o[8];
#pragma unroll
            for (int c = 0; c < 8; ++c) o[c] = silu_f(acc[i][c] + brr[c]);
            float4 v0 = make_float4(o[0], o[1], o[2], o[3]);
            float4 v1 = make_float4(o[4], o[5], o[6], o[7]);
            *(float4*)(Y + (size_t)row * EMB + j0)     = v0;
            *(float4*)(Y + (size_t)row * EMB + j0 + 4) = v1;
        }
    }
}

// ---------------------------------------------------------------------------
// Final projection: out[i] = dot(A[i], Wf) * cf
// ---------------------------------------------------------------------------
__global__ __launch_bounds__(256)
void final_kernel(const float* __restrict__ A,
                  const float* __restrict__ Wf,
                  const float* __restrict__ cf,
                  float* __restrict__ out)
{
    const int i = blockIdx.x * blockDim.x + threadIdx.x;
    if (i >= NATOMS) return;
    const float4* row = (const float4*)(A + (size_t)i * EMB);
    const float4* w   = (const float4*)Wf;
    float acc = 0.f;
#pragma unroll
    for (int k = 0; k < EMB / 4; ++k) {
        const float4 a = row[k];
        const float4 b = w[k];
        acc = __builtin_fmaf(a.x, b.x, acc);
        acc = __builtin_fmaf(a.y, b.y, acc);
        acc = __builtin_fmaf(a.z, b.z, acc);
        acc = __builtin_fmaf(a.w, b.w, acc);
    }
    out[i] = acc * cf[0];
}

extern "C" void kernel_launch(void* const* d_in, const int* in_sizes, int n_in,
                              void* d_out, int out_size, void* d_ws, size_t ws_size,
                              hipStream_t stream) {
    const float* x    = (const float*)d_in[0];
    const float* rbf  = (const float*)d_in[1];
    const int*   idnb = (const int*)  d_in[2];
    // d_in[3] = n_atoms (fixed 50000)
    const float* Wx   = (const float*)d_in[4];
    const float* bx   = (const float*)d_in[5];
    const float* Wr   = (const float*)d_in[6];
    const float* brf  = (const float*)d_in[7];
    const float* W1   = (const float*)d_in[8];
    const float* b1   = (const float*)d_in[9];
    const float* W2   = (const float*)d_in[10];
    const float* b2   = (const float*)d_in[11];
    const float* W3   = (const float*)d_in[12];
    const float* b3   = (const float*)d_in[13];
    const float* Wf   = (const float*)d_in[14];
    const float* c_a  = (const float*)d_in[15];
    const float* c_b  = (const float*)d_in[16];
    const float* c_x  = (const float*)d_in[17];
    const float* c_f  = (const float*)d_in[18];

    float* out = (float*)d_out;
    float* acc = (float*)d_ws;                       // [NATOMS][128]
    float* buf = acc + (size_t)NATOMS * EMB;         // [NATOMS][128]

    // accumulator must be zero every call (ws is poisoned once, not restored)
    hipMemsetAsync(acc, 0, (size_t)NATOMS * EMB * sizeof(float), stream);

    edge_kernel<<<1024, 256, 0, stream>>>(x, rbf, idnb, Wx, bx, Wr, brf,
                                          c_a, c_b, c_x, acc);

    const int atiles = (NATOMS + 63) / 64;           // 782
    layer_kernel<<<atiles, 256, 0, stream>>>(acc, W1, b1, buf, NATOMS);
    layer_kernel<<<atiles, 256, 0, stream>>>(buf, W2, b2, acc, NATOMS);
    layer_kernel<<<atiles, 256, 0, stream>>>(acc, W3, b3, buf, NATOMS);

    final_kernel<<<(NATOMS + 255) / 256, 256, 0, stream>>>(buf, Wf, c_f, out);
}

// Round 3
// 3288.927 us; speedup vs baseline: 1.1546x; 1.1545x over previous
//
#include <hip/hip_runtime.h>

#define E_TOTAL 1000000
#define EMB     128
#define NRBF    16
#define NATOMS  50000

__device__ __forceinline__ float silu_f(float v) {
    return v * (1.0f / (1.0f + __expf(-v)));
}

// ---------------------------------------------------------------------------
// CSR build: counting sort of edge ids by destination atom.
// ---------------------------------------------------------------------------
__global__ __launch_bounds__(256)
void hist_kernel(const int* __restrict__ idnb, int* __restrict__ counts) {
    const int e = blockIdx.x * 256 + threadIdx.x;
    if (e < E_TOTAL) atomicAdd(&counts[idnb[e]], 1);
}

// Single-block exclusive scan of counts -> cursor (Hillis-Steele per chunk).
__global__ __launch_bounds__(256)
void scan_kernel(const int* __restrict__ counts, int* __restrict__ cursor) {
    __shared__ int sdata[256];
    __shared__ int sbase;
    if (threadIdx.x == 0) sbase = 0;
    __syncthreads();
    for (int base = 0; base < NATOMS; base += 256) {
        const int idx = base + threadIdx.x;
        const int v = (idx < NATOMS) ? counts[idx] : 0;
        sdata[threadIdx.x] = v;
        __syncthreads();
#pragma unroll
        for (int off = 1; off < 256; off <<= 1) {
            const int t = (threadIdx.x >= off) ? sdata[threadIdx.x - off] : 0;
            __syncthreads();
            sdata[threadIdx.x] += t;
            __syncthreads();
        }
        const int excl = sdata[threadIdx.x] - v + sbase;
        if (idx < NATOMS) cursor[idx] = excl;
        __syncthreads();
        if (threadIdx.x == 255) sbase += sdata[255];
        __syncthreads();
    }
}

__global__ __launch_bounds__(256)
void scatter_kernel(const int* __restrict__ idnb, int* __restrict__ cursor,
                    int* __restrict__ eidx) {
    const int e = blockIdx.x * 256 + threadIdx.x;
    if (e < E_TOTAL) {
        const int p = atomicAdd(&cursor[idnb[e]], 1);
        eidx[p] = e;
    }
}

// ---------------------------------------------------------------------------
// Edge kernel (atom-sorted order): per edge e = eidx[...]
//   h = silu(x[e] @ Wx + bx); g = silu((ca*rbf[e]) @ Wr + br)
//   acc[idnb[e]] += (cb*cx) * g * h
// Tile: 64 sorted edges / block-iter; thread tile 4 edges x 8 cols.
// Per-thread run-merge before atomics (sorted => same-atom runs avg ~20).
// ---------------------------------------------------------------------------
__global__ __launch_bounds__(256, 4)
void edge_kernel(const float* __restrict__ x,
                 const float* __restrict__ rbf,
                 const int*   __restrict__ idnb,
                 const int*   __restrict__ eidx,
                 const float* __restrict__ Wx,
                 const float* __restrict__ bx,
                 const float* __restrict__ Wr,
                 const float* __restrict__ br,
                 const float* __restrict__ c_a,
                 const float* __restrict__ c_b,
                 const float* __restrict__ c_x,
                 float* __restrict__ acc)
{
    __shared__ float sX[64][132];   // +4 pad words -> conflict-free quad reads
    __shared__ float sR[64][20];
    __shared__ int   sEid[64];
    __shared__ int   sAidx[64];

    const int tid = threadIdx.x;
    const int tx  = tid & 15;       // 16 col groups of 8
    const int ty  = tid >> 4;       // 16 edge groups of 4
    const int j0  = tx * 8;
    const int e0  = ty * 4;

    const float ca = c_a[0];
    const float sc = c_b[0] * c_x[0];

    float bxr[8], brr[8];
#pragma unroll
    for (int c = 0; c < 8; ++c) { bxr[c] = bx[j0 + c]; brr[c] = br[j0 + c]; }

    const int ntiles = E_TOTAL / 64;   // 15625, exact
    for (int tile = blockIdx.x; tile < ntiles; tile += gridDim.x) {
        const int base = tile * 64;
        __syncthreads();   // protect LDS from previous iteration's readers
        if (tid < 64) {
            const int eid = eidx[base + tid];
            sEid[tid]  = eid;
            sAidx[tid] = idnb[eid];
        }
        __syncthreads();
        // gather x rows (each half-wave reads one contiguous 512B row)
#pragma unroll
        for (int i = 0; i < 8; ++i) {
            const int f = tid + i * 256;
            const int e = f >> 5, seg = f & 31;
            const float4 v = *(const float4*)(x + (size_t)sEid[e] * EMB + seg * 4);
            *(float4*)&sX[e][seg * 4] = v;
        }
        {
            const int e = tid >> 2, seg = tid & 3;
            const float4 v = *(const float4*)(rbf + (size_t)sEid[e] * NRBF + seg * 4);
            *(float4*)&sR[e][seg * 4] = v;
        }
        __syncthreads();

        float hacc[4][8];
        float gacc[4][8];
#pragma unroll
        for (int i = 0; i < 4; ++i)
#pragma unroll
            for (int c = 0; c < 8; ++c) { hacc[i][c] = 0.f; gacc[i][c] = 0.f; }

        // ---- g accumulation: K = 16 ----
#pragma unroll
        for (int kq = 0; kq < NRBF / 4; ++kq) {
            const int k = kq * 4;
            float xa[4][4];
#pragma unroll
            for (int i = 0; i < 4; ++i) {
                const float4 v = *(const float4*)&sR[e0 + i][k];
                xa[i][0] = v.x; xa[i][1] = v.y; xa[i][2] = v.z; xa[i][3] = v.w;
            }
#pragma unroll
            for (int kk = 0; kk < 4; ++kk) {
                const float4 w0 = *(const float4*)(Wr + (size_t)(k + kk) * EMB + j0);
                const float4 w1 = *(const float4*)(Wr + (size_t)(k + kk) * EMB + j0 + 4);
                const float wv[8] = {w0.x, w0.y, w0.z, w0.w, w1.x, w1.y, w1.z, w1.w};
#pragma unroll
                for (int i = 0; i < 4; ++i) {
                    const float xv = xa[i][kk];
#pragma unroll
                    for (int c = 0; c < 8; ++c)
                        gacc[i][c] = __builtin_fmaf(xv, wv[c], gacc[i][c]);
                }
            }
        }

        // ---- h accumulation: K = 128 ----
#pragma unroll 2
        for (int kq = 0; kq < EMB / 4; ++kq) {
            const int k = kq * 4;
            float xa[4][4];
#pragma unroll
            for (int i = 0; i < 4; ++i) {
                const float4 v = *(const float4*)&sX[e0 + i][k];
                xa[i][0] = v.x; xa[i][1] = v.y; xa[i][2] = v.z; xa[i][3] = v.w;
            }
#pragma unroll
            for (int kk = 0; kk < 4; ++kk) {
                const float4 w0 = *(const float4*)(Wx + (size_t)(k + kk) * EMB + j0);
                const float4 w1 = *(const float4*)(Wx + (size_t)(k + kk) * EMB + j0 + 4);
                const float wv[8] = {w0.x, w0.y, w0.z, w0.w, w1.x, w1.y, w1.z, w1.w};
#pragma unroll
                for (int i = 0; i < 4; ++i) {
                    const float xv = xa[i][kk];
#pragma unroll
                    for (int c = 0; c < 8; ++c)
                        hacc[i][c] = __builtin_fmaf(xv, wv[c], hacc[i][c]);
                }
            }
        }

        // ---- gate (store into hacc), then run-merged scatter-add ----
#pragma unroll
        for (int i = 0; i < 4; ++i) {
#pragma unroll
            for (int c = 0; c < 8; ++c) {
                const float h = silu_f(hacc[i][c] + bxr[c]);
                const float g = silu_f(__builtin_fmaf(gacc[i][c], ca, brr[c]));
                hacc[i][c] = sc * g * h;
            }
        }
        int cur = sAidx[e0];
        float vals[8];
#pragma unroll
        for (int c = 0; c < 8; ++c) vals[c] = hacc[0][c];
#pragma unroll
        for (int i = 1; i < 4; ++i) {
            const int a = sAidx[e0 + i];
            if (a == cur) {
#pragma unroll
                for (int c = 0; c < 8; ++c) vals[c] += hacc[i][c];
            } else {
                float* dst = acc + (size_t)cur * EMB + j0;
#pragma unroll
                for (int c = 0; c < 8; ++c) unsafeAtomicAdd(dst + c, vals[c]);
                cur = a;
#pragma unroll
                for (int c = 0; c < 8; ++c) vals[c] = hacc[i][c];
            }
        }
        {
            float* dst = acc + (size_t)cur * EMB + j0;
#pragma unroll
            for (int c = 0; c < 8; ++c) unsafeAtomicAdd(dst + c, vals[c]);
        }
    }
}

// ---------------------------------------------------------------------------
// Atom MLP layer: Y = silu(X @ W + b)
// ---------------------------------------------------------------------------
__global__ __launch_bounds__(256, 2)
void layer_kernel(const float* __restrict__ X,
                  const float* __restrict__ W,
                  const float* __restrict__ b,
                  float* __restrict__ Y,
                  int M)
{
    __shared__ float sX[64][132];

    const int tid = threadIdx.x;
    const int tx  = tid & 15;
    const int ty  = tid >> 4;
    const int j0  = tx * 8;
    const int e0  = ty * 4;

    float brr[8];
#pragma unroll
    for (int c = 0; c < 8; ++c) brr[c] = b[j0 + c];

    const int base = blockIdx.x * 64;
#pragma unroll
    for (int i = 0; i < 8; ++i) {
        const int f = tid + i * 256;
        const int e = f >> 5, seg = f & 31;
        const int row = base + e;
        float4 v = make_float4(0.f, 0.f, 0.f, 0.f);
        if (row < M) v = *(const float4*)(X + (size_t)row * EMB + seg * 4);
        *(float4*)&sX[e][seg * 4] = v;
    }
    __syncthreads();

    float acc[4][8];
#pragma unroll
    for (int i = 0; i < 4; ++i)
#pragma unroll
        for (int c = 0; c < 8; ++c) acc[i][c] = 0.f;

#pragma unroll 2
    for (int kq = 0; kq < EMB / 4; ++kq) {
        const int k = kq * 4;
        float xa[4][4];
#pragma unroll
        for (int i = 0; i < 4; ++i) {
            const float4 v = *(const float4*)&sX[e0 + i][k];
            xa[i][0] = v.x; xa[i][1] = v.y; xa[i][2] = v.z; xa[i][3] = v.w;
        }
#pragma unroll
        for (int kk = 0; kk < 4; ++kk) {
            const float4 w0 = *(const float4*)(W + (size_t)(k + kk) * EMB + j0);
            const float4 w1 = *(const float4*)(W + (size_t)(k + kk) * EMB + j0 + 4);
            const float wv[8] = {w0.x, w0.y, w0.z, w0.w, w1.x, w1.y, w1.z, w1.w};
#pragma unroll
            for (int i = 0; i < 4; ++i) {
                const float xv = xa[i][kk];
#pragma unroll
                for (int c = 0; c < 8; ++c)
                    acc[i][c] = __builtin_fmaf(xv, wv[c], acc[i][c]);
            }
        }
    }

#pragma unroll
    for (int i = 0; i < 4; ++i) {
        const int row = base + e0 + i;
        if (row < M) {
            float o[8];
#pragma unroll
            for (int c = 0; c < 8; ++c) o[c] = silu_f(acc[i][c] + brr[c]);
            float4 v0 = make_float4(o[0], o[1], o[2], o[3]);
            float4 v1 = make_float4(o[4], o[5], o[6], o[7]);
            *(float4*)(Y + (size_t)row * EMB + j0)     = v0;
            *(float4*)(Y + (size_t)row * EMB + j0 + 4) = v1;
        }
    }
}

// ---------------------------------------------------------------------------
// Final projection: out[i] = dot(A[i], Wf) * cf
// ---------------------------------------------------------------------------
__global__ __launch_bounds__(256)
void final_kernel(const float* __restrict__ A,
                  const float* __restrict__ Wf,
                  const float* __restrict__ cf,
                  float* __restrict__ out)
{
    const int i = blockIdx.x * blockDim.x + threadIdx.x;
    if (i >= NATOMS) return;
    const float4* row = (const float4*)(A + (size_t)i * EMB);
    const float4* w   = (const float4*)Wf;
    float acc = 0.f;
#pragma unroll
    for (int k = 0; k < EMB / 4; ++k) {
        const float4 a = row[k];
        const float4 b = w[k];
        acc = __builtin_fmaf(a.x, b.x, acc);
        acc = __builtin_fmaf(a.y, b.y, acc);
        acc = __builtin_fmaf(a.z, b.z, acc);
        acc = __builtin_fmaf(a.w, b.w, acc);
    }
    out[i] = acc * cf[0];
}

extern "C" void kernel_launch(void* const* d_in, const int* in_sizes, int n_in,
                              void* d_out, int out_size, void* d_ws, size_t ws_size,
                              hipStream_t stream) {
    const float* x    = (const float*)d_in[0];
    const float* rbf  = (const float*)d_in[1];
    const int*   idnb = (const int*)  d_in[2];
    // d_in[3] = n_atoms (fixed 50000)
    const float* Wx   = (const float*)d_in[4];
    const float* bx   = (const float*)d_in[5];
    const float* Wr   = (const float*)d_in[6];
    const float* brf  = (const float*)d_in[7];
    const float* W1   = (const float*)d_in[8];
    const float* b1   = (const float*)d_in[9];
    const float* W2   = (const float*)d_in[10];
    const float* b2   = (const float*)d_in[11];
    const float* W3   = (const float*)d_in[12];
    const float* b3   = (const float*)d_in[13];
    const float* Wf   = (const float*)d_in[14];
    const float* c_a  = (const float*)d_in[15];
    const float* c_b  = (const float*)d_in[16];
    const float* c_x  = (const float*)d_in[17];
    const float* c_f  = (const float*)d_in[18];

    float* out = (float*)d_out;
    float* acc = (float*)d_ws;                        // [NATOMS][128] floats
    float* buf = acc + (size_t)NATOMS * EMB;          // [NATOMS][128] floats
    // CSR scratch overlaps buf: eidx is dead once edge_kernel completes,
    // and buf is first written by layer 1 (stream-ordered after edge_kernel).
    int*   eidx   = (int*)buf;                        // 1M ints (4 MB)
    int*   counts = eidx + E_TOTAL;                   // 50048 ints
    int*   cursor = counts + 50048;                   // 50048 ints

    // zero accumulator + histogram every call (ws not re-poisoned by harness)
    hipMemsetAsync(acc, 0, (size_t)NATOMS * EMB * sizeof(float), stream);
    hipMemsetAsync(counts, 0, 50048 * sizeof(int), stream);

    hist_kernel<<<(E_TOTAL + 255) / 256, 256, 0, stream>>>(idnb, counts);
    scan_kernel<<<1, 256, 0, stream>>>(counts, cursor);
    scatter_kernel<<<(E_TOTAL + 255) / 256, 256, 0, stream>>>(idnb, cursor, eidx);

    edge_kernel<<<2048, 256, 0, stream>>>(x, rbf, idnb, eidx, Wx, bx, Wr, brf,
                                          c_a, c_b, c_x, acc);

    const int atiles = (NATOMS + 63) / 64;            // 782
    layer_kernel<<<atiles, 256, 0, stream>>>(acc, W1, b1, buf, NATOMS);
    layer_kernel<<<atiles, 256, 0, stream>>>(buf, W2, b2, acc, NATOMS);
    layer_kernel<<<atiles, 256, 0, stream>>>(acc, W3, b3, buf, NATOMS);

    final_kernel<<<(NATOMS + 255) / 256, 256, 0, stream>>>(buf, Wf, c_f, out);
}

// Round 4
// 2059.133 us; speedup vs baseline: 1.8442x; 1.5972x over previous
//
#include <hip/hip_runtime.h>

#define E_TOTAL 1000000
#define EMB     128
#define NRBF    16
#define NATOMS  50000
#define APB     16                         // atoms per block (50000 = 3125*16)
#define NBLK    ((NATOMS + 255) / 256)     // 196 scan blocks

__device__ __forceinline__ float silu_f(float v) {
    return v * (1.0f / (1.0f + __expf(-v)));
}

// ---------------------------------------------------------------------------
// CSR build: counting sort of edge ids by destination atom.
// ---------------------------------------------------------------------------
__global__ __launch_bounds__(256)
void hist_kernel(const int* __restrict__ idnb, int* __restrict__ counts) {
    const int e = blockIdx.x * 256 + threadIdx.x;
    if (e < E_TOTAL) atomicAdd(&counts[idnb[e]], 1);
}

// Phase 1: per-256-chunk exclusive scan + chunk totals.
__global__ __launch_bounds__(256)
void scan1_kernel(const int* __restrict__ counts, int* __restrict__ row_ptr,
                  int* __restrict__ bsums) {
    __shared__ int sd[256];
    const int tid = threadIdx.x;
    const int idx = blockIdx.x * 256 + tid;
    const int v = (idx < NATOMS) ? counts[idx] : 0;
    sd[tid] = v;
    __syncthreads();
#pragma unroll
    for (int off = 1; off < 256; off <<= 1) {
        const int t = (tid >= off) ? sd[tid - off] : 0;
        __syncthreads();
        sd[tid] += t;
        __syncthreads();
    }
    if (idx < NATOMS) row_ptr[idx] = sd[tid] - v;   // exclusive within chunk
    if (tid == 255) bsums[blockIdx.x] = sd[255];
}

// Phase 2: single block scans the 196 chunk totals (exclusive, in place).
__global__ __launch_bounds__(256)
void scan2_kernel(int* __restrict__ bsums) {
    __shared__ int sd[256];
    const int tid = threadIdx.x;
    const int v = (tid < NBLK) ? bsums[tid] : 0;
    sd[tid] = v;
    __syncthreads();
#pragma unroll
    for (int off = 1; off < 256; off <<= 1) {
        const int t = (tid >= off) ? sd[tid - off] : 0;
        __syncthreads();
        sd[tid] += t;
        __syncthreads();
    }
    if (tid < NBLK) bsums[tid] = sd[tid] - v;
}

// Phase 3: add chunk offsets; produce row_ptr (kept) and cursor (mutable copy).
__global__ __launch_bounds__(256)
void scan3_kernel(const int* __restrict__ bsums, int* __restrict__ row_ptr,
                  int* __restrict__ cursor) {
    const int idx = blockIdx.x * 256 + threadIdx.x;
    if (idx < NATOMS) {
        const int r = row_ptr[idx] + bsums[blockIdx.x];
        row_ptr[idx] = r;
        cursor[idx]  = r;
    }
    if (idx == 0) row_ptr[NATOMS] = E_TOTAL;
}

// Scatter: sorted edge-id list + sorted atom-id list.
__global__ __launch_bounds__(256)
void scatter_kernel(const int* __restrict__ idnb, int* __restrict__ cursor,
                    int* __restrict__ eidx, int* __restrict__ aidxs) {
    const int e = blockIdx.x * 256 + threadIdx.x;
    if (e < E_TOTAL) {
        const int a = idnb[e];
        const int p = atomicAdd(&cursor[a], 1);
        eidx[p]  = e;
        aidxs[p] = a;
    }
}

// ---------------------------------------------------------------------------
// Edge kernel, CSR atom-ownership: block b owns atoms [16b, 16b+16) and ALL
// their edges [row_ptr[a0], row_ptr[a0+16]). Gated conv values are merged in
// registers (sorted runs), atomically added to a 16-row LDS accumulator, and
// each atom row is written to global exactly ONCE with plain stores.
// Zero global atomics; acc needs no pre-zeroing.
// ---------------------------------------------------------------------------
__global__ __launch_bounds__(256, 3)
void edge_kernel(const float* __restrict__ x,
                 const float* __restrict__ rbf,
                 const int*   __restrict__ eidx,
                 const int*   __restrict__ aidxs,
                 const int*   __restrict__ row_ptr,
                 const float* __restrict__ Wx,
                 const float* __restrict__ bx,
                 const float* __restrict__ Wr,
                 const float* __restrict__ br,
                 const float* __restrict__ c_a,
                 const float* __restrict__ c_b,
                 const float* __restrict__ c_x,
                 float* __restrict__ acc)
{
    __shared__ float sAcc[APB][132];  // 8.4 KB  per-block atom accumulator
    __shared__ float sX[64][132];     // 33.8 KB (+4 pad -> conflict-free quads)
    __shared__ float sR[64][20];      // 5.1 KB
    __shared__ int   sEid[64];
    __shared__ int   sRel[64];

    const int tid = threadIdx.x;
    const int tx  = tid & 15;         // 16 col groups of 8
    const int ty  = tid >> 4;         // 16 edge groups of 4
    const int j0  = tx * 8;
    const int e0  = ty * 4;

    const int a0   = blockIdx.x * APB;
    const int eBeg = row_ptr[a0];
    const int eEnd = row_ptr[a0 + APB];

    const float ca = c_a[0];
    const float sc = c_b[0] * c_x[0];

    float bxr[8], brr[8];
#pragma unroll
    for (int c = 0; c < 8; ++c) { bxr[c] = bx[j0 + c]; brr[c] = br[j0 + c]; }

    // zero the LDS accumulator
    for (int f = tid; f < APB * 132; f += 256) ((float*)sAcc)[f] = 0.f;

    for (int base = eBeg; base < eEnd; base += 64) {
        const int n = min(64, eEnd - base);
        __syncthreads();   // sAcc zero done / previous iteration's readers done
        if (tid < 64) {
            if (tid < n) {
                sEid[tid] = eidx[base + tid];
                sRel[tid] = aidxs[base + tid] - a0;
            } else {
                sEid[tid] = -1;
                sRel[tid] = -1;
            }
        }
        __syncthreads();
        // gather x rows (each half-wave reads one contiguous 512B row)
#pragma unroll
        for (int i = 0; i < 8; ++i) {
            const int f = tid + i * 256;
            const int e = f >> 5, seg = f & 31;
            const int eid = sEid[e];
            if (eid >= 0) {
                const float4 v = *(const float4*)(x + (size_t)eid * EMB + seg * 4);
                *(float4*)&sX[e][seg * 4] = v;
            }
        }
        {
            const int e = tid >> 2, seg = tid & 3;
            const int eid = sEid[e];
            if (eid >= 0) {
                const float4 v = *(const float4*)(rbf + (size_t)eid * NRBF + seg * 4);
                *(float4*)&sR[e][seg * 4] = v;
            }
        }
        __syncthreads();

        float hacc[4][8];
        float gacc[4][8];
#pragma unroll
        for (int i = 0; i < 4; ++i)
#pragma unroll
            for (int c = 0; c < 8; ++c) { hacc[i][c] = 0.f; gacc[i][c] = 0.f; }

        // ---- g accumulation: K = 16 ----
#pragma unroll
        for (int kq = 0; kq < NRBF / 4; ++kq) {
            const int k = kq * 4;
            float xa[4][4];
#pragma unroll
            for (int i = 0; i < 4; ++i) {
                const float4 v = *(const float4*)&sR[e0 + i][k];
                xa[i][0] = v.x; xa[i][1] = v.y; xa[i][2] = v.z; xa[i][3] = v.w;
            }
#pragma unroll
            for (int kk = 0; kk < 4; ++kk) {
                const float4 w0 = *(const float4*)(Wr + (size_t)(k + kk) * EMB + j0);
                const float4 w1 = *(const float4*)(Wr + (size_t)(k + kk) * EMB + j0 + 4);
                const float wv[8] = {w0.x, w0.y, w0.z, w0.w, w1.x, w1.y, w1.z, w1.w};
#pragma unroll
                for (int i = 0; i < 4; ++i) {
                    const float xv = xa[i][kk];
#pragma unroll
                    for (int c = 0; c < 8; ++c)
                        gacc[i][c] = __builtin_fmaf(xv, wv[c], gacc[i][c]);
                }
            }
        }

        // ---- h accumulation: K = 128 ----
#pragma unroll 2
        for (int kq = 0; kq < EMB / 4; ++kq) {
            const int k = kq * 4;
            float xa[4][4];
#pragma unroll
            for (int i = 0; i < 4; ++i) {
                const float4 v = *(const float4*)&sX[e0 + i][k];
                xa[i][0] = v.x; xa[i][1] = v.y; xa[i][2] = v.z; xa[i][3] = v.w;
            }
#pragma unroll
            for (int kk = 0; kk < 4; ++kk) {
                const float4 w0 = *(const float4*)(Wx + (size_t)(k + kk) * EMB + j0);
                const float4 w1 = *(const float4*)(Wx + (size_t)(k + kk) * EMB + j0 + 4);
                const float wv[8] = {w0.x, w0.y, w0.z, w0.w, w1.x, w1.y, w1.z, w1.w};
#pragma unroll
                for (int i = 0; i < 4; ++i) {
                    const float xv = xa[i][kk];
#pragma unroll
                    for (int c = 0; c < 8; ++c)
                        hacc[i][c] = __builtin_fmaf(xv, wv[c], hacc[i][c]);
                }
            }
        }

        // ---- gate, register-merge sorted runs, LDS atomic add ----
#pragma unroll
        for (int i = 0; i < 4; ++i) {
#pragma unroll
            for (int c = 0; c < 8; ++c) {
                const float h = silu_f(hacc[i][c] + bxr[c]);
                const float g = silu_f(__builtin_fmaf(gacc[i][c], ca, brr[c]));
                hacc[i][c] = sc * g * h;
            }
        }
        int cur = sRel[e0];
        float vals[8];
#pragma unroll
        for (int c = 0; c < 8; ++c) vals[c] = hacc[0][c];
#pragma unroll
        for (int i = 1; i < 4; ++i) {
            const int a = sRel[e0 + i];
            if (a == cur) {
#pragma unroll
                for (int c = 0; c < 8; ++c) vals[c] += hacc[i][c];
            } else {
                if (cur >= 0) {
#pragma unroll
                    for (int c = 0; c < 8; ++c)
                        atomicAdd(&sAcc[cur][j0 + c], vals[c]);
                }
                cur = a;
#pragma unroll
                for (int c = 0; c < 8; ++c) vals[c] = hacc[i][c];
            }
        }
        if (cur >= 0) {
#pragma unroll
            for (int c = 0; c < 8; ++c) atomicAdd(&sAcc[cur][j0 + c], vals[c]);
        }
    }

    // ---- write 16 owned atom rows exactly once (plain stores) ----
    __syncthreads();
    {
        const int r = tid >> 4;            // 0..15
        const int col = (tid & 15) * 8;
        float* dst = acc + (size_t)(a0 + r) * EMB + col;
        *(float4*)(dst)     = *(const float4*)&sAcc[r][col];
        *(float4*)(dst + 4) = *(const float4*)&sAcc[r][col + 4];
    }
}

// ---------------------------------------------------------------------------
// Atom MLP layer: Y = silu(X @ W + b)
// ---------------------------------------------------------------------------
__global__ __launch_bounds__(256, 2)
void layer_kernel(const float* __restrict__ X,
                  const float* __restrict__ W,
                  const float* __restrict__ b,
                  float* __restrict__ Y,
                  int M)
{
    __shared__ float sX[64][132];

    const int tid = threadIdx.x;
    const int tx  = tid & 15;
    const int ty  = tid >> 4;
    const int j0  = tx * 8;
    const int e0  = ty * 4;

    float brr[8];
#pragma unroll
    for (int c = 0; c < 8; ++c) brr[c] = b[j0 + c];

    const int base = blockIdx.x * 64;
#pragma unroll
    for (int i = 0; i < 8; ++i) {
        const int f = tid + i * 256;
        const int e = f >> 5, seg = f & 31;
        const int row = base + e;
        float4 v = make_float4(0.f, 0.f, 0.f, 0.f);
        if (row < M) v = *(const float4*)(X + (size_t)row * EMB + seg * 4);
        *(float4*)&sX[e][seg * 4] = v;
    }
    __syncthreads();

    float acc[4][8];
#pragma unroll
    for (int i = 0; i < 4; ++i)
#pragma unroll
        for (int c = 0; c < 8; ++c) acc[i][c] = 0.f;

#pragma unroll 2
    for (int kq = 0; kq < EMB / 4; ++kq) {
        const int k = kq * 4;
        float xa[4][4];
#pragma unroll
        for (int i = 0; i < 4; ++i) {
            const float4 v = *(const float4*)&sX[e0 + i][k];
            xa[i][0] = v.x; xa[i][1] = v.y; xa[i][2] = v.z; xa[i][3] = v.w;
        }
#pragma unroll
        for (int kk = 0; kk < 4; ++kk) {
            const float4 w0 = *(const float4*)(W + (size_t)(k + kk) * EMB + j0);
            const float4 w1 = *(const float4*)(W + (size_t)(k + kk) * EMB + j0 + 4);
            const float wv[8] = {w0.x, w0.y, w0.z, w0.w, w1.x, w1.y, w1.z, w1.w};
#pragma unroll
            for (int i = 0; i < 4; ++i) {
                const float xv = xa[i][kk];
#pragma unroll
                for (int c = 0; c < 8; ++c)
                    acc[i][c] = __builtin_fmaf(xv, wv[c], acc[i][c]);
            }
        }
    }

#pragma unroll
    for (int i = 0; i < 4; ++i) {
        const int row = base + e0 + i;
        if (row < M) {
            float o[8];
#pragma unroll
            for (int c = 0; c < 8; ++c) o[c] = silu_f(acc[i][c] + brr[c]);
            float4 v0 = make_float4(o[0], o[1], o[2], o[3]);
            float4 v1 = make_float4(o[4], o[5], o[6], o[7]);
            *(float4*)(Y + (size_t)row * EMB + j0)     = v0;
            *(float4*)(Y + (size_t)row * EMB + j0 + 4) = v1;
        }
    }
}

// ---------------------------------------------------------------------------
// Final projection: out[i] = dot(A[i], Wf) * cf
// ---------------------------------------------------------------------------
__global__ __launch_bounds__(256)
void final_kernel(const float* __restrict__ A,
                  const float* __restrict__ Wf,
                  const float* __restrict__ cf,
                  float* __restrict__ out)
{
    const int i = blockIdx.x * blockDim.x + threadIdx.x;
    if (i >= NATOMS) return;
    const float4* row = (const float4*)(A + (size_t)i * EMB);
    const float4* w   = (const float4*)Wf;
    float acc = 0.f;
#pragma unroll
    for (int k = 0; k < EMB / 4; ++k) {
        const float4 a = row[k];
        const float4 b = w[k];
        acc = __builtin_fmaf(a.x, b.x, acc);
        acc = __builtin_fmaf(a.y, b.y, acc);
        acc = __builtin_fmaf(a.z, b.z, acc);
        acc = __builtin_fmaf(a.w, b.w, acc);
    }
    out[i] = acc * cf[0];
}

extern "C" void kernel_launch(void* const* d_in, const int* in_sizes, int n_in,
                              void* d_out, int out_size, void* d_ws, size_t ws_size,
                              hipStream_t stream) {
    const float* x    = (const float*)d_in[0];
    const float* rbf  = (const float*)d_in[1];
    const int*   idnb = (const int*)  d_in[2];
    // d_in[3] = n_atoms (fixed 50000)
    const float* Wx   = (const float*)d_in[4];
    const float* bx   = (const float*)d_in[5];
    const float* Wr   = (const float*)d_in[6];
    const float* brf  = (const float*)d_in[7];
    const float* W1   = (const float*)d_in[8];
    const float* b1   = (const float*)d_in[9];
    const float* W2   = (const float*)d_in[10];
    const float* b2   = (const float*)d_in[11];
    const float* W3   = (const float*)d_in[12];
    const float* b3   = (const float*)d_in[13];
    const float* Wf   = (const float*)d_in[14];
    const float* c_a  = (const float*)d_in[15];
    const float* c_b  = (const float*)d_in[16];
    const float* c_x  = (const float*)d_in[17];
    const float* c_f  = (const float*)d_in[18];

    float* out = (float*)d_out;
    float* acc = (float*)d_ws;                        // [NATOMS][128] floats
    float* buf = acc + (size_t)NATOMS * EMB;          // [NATOMS][128] floats
    // CSR scratch overlaps buf: all of it is dead once edge_kernel completes,
    // and buf is first written by layer 1 (stream-ordered after edge_kernel).
    int* eidx    = (int*)buf;                         // 1M
    int* aidxs   = eidx + E_TOTAL;                    // 1M
    int* counts  = aidxs + E_TOTAL;                   // NATOMS
    int* row_ptr = counts + NATOMS;                   // NATOMS+1
    int* cursor  = row_ptr + NATOMS + 1;              // NATOMS
    int* bsums   = cursor + NATOMS;                   // NBLK

    hipMemsetAsync(counts, 0, NATOMS * sizeof(int), stream);

    hist_kernel<<<(E_TOTAL + 255) / 256, 256, 0, stream>>>(idnb, counts);
    scan1_kernel<<<NBLK, 256, 0, stream>>>(counts, row_ptr, bsums);
    scan2_kernel<<<1, 256, 0, stream>>>(bsums);
    scan3_kernel<<<NBLK, 256, 0, stream>>>(bsums, row_ptr, cursor);
    scatter_kernel<<<(E_TOTAL + 255) / 256, 256, 0, stream>>>(idnb, cursor, eidx, aidxs);

    edge_kernel<<<NATOMS / APB, 256, 0, stream>>>(x, rbf, eidx, aidxs, row_ptr,
                                                  Wx, bx, Wr, brf,
                                                  c_a, c_b, c_x, acc);

    const int atiles = (NATOMS + 63) / 64;            // 782
    layer_kernel<<<atiles, 256, 0, stream>>>(acc, W1, b1, buf, NATOMS);
    layer_kernel<<<atiles, 256, 0, stream>>>(buf, W2, b2, acc, NATOMS);
    layer_kernel<<<atiles, 256, 0, stream>>>(acc, W3, b3, buf, NATOMS);

    final_kernel<<<(NATOMS + 255) / 256, 256, 0, stream>>>(buf, Wf, c_f, out);
}

// Round 5
// 758.818 us; speedup vs baseline: 5.0045x; 2.7136x over previous
//
#include <hip/hip_runtime.h>

#define E_TOTAL 1000000
#define EMB     128
#define NRBF    16
#define NATOMS  50000
#define APB     16                         // atoms per block (50000 = 3125*16)
#define NBLK    ((NATOMS + 255) / 256)     // scan blocks

typedef _Float16 f16x8 __attribute__((ext_vector_type(8)));
typedef _Float16 f16x4 __attribute__((ext_vector_type(4)));
typedef float    f32x4 __attribute__((ext_vector_type(4)));

__device__ __forceinline__ float silu_f(float v) {
    return v * (1.0f / (1.0f + __expf(-v)));
}

// ---------------------------------------------------------------------------
// CSR build: counting sort of edge ids by destination atom.
// ---------------------------------------------------------------------------
__global__ __launch_bounds__(256)
void hist_kernel(const int* __restrict__ idnb, int* __restrict__ counts) {
    const int e = blockIdx.x * 256 + threadIdx.x;
    if (e < E_TOTAL) atomicAdd(&counts[idnb[e]], 1);
}

__global__ __launch_bounds__(256)
void scan1_kernel(const int* __restrict__ counts, int* __restrict__ row_ptr,
                  int* __restrict__ bsums) {
    __shared__ int sd[256];
    const int tid = threadIdx.x;
    const int idx = blockIdx.x * 256 + tid;
    const int v = (idx < NATOMS) ? counts[idx] : 0;
    sd[tid] = v;
    __syncthreads();
#pragma unroll
    for (int off = 1; off < 256; off <<= 1) {
        const int t = (tid >= off) ? sd[tid - off] : 0;
        __syncthreads();
        sd[tid] += t;
        __syncthreads();
    }
    if (idx < NATOMS) row_ptr[idx] = sd[tid] - v;
    if (tid == 255) bsums[blockIdx.x] = sd[255];
}

__global__ __launch_bounds__(256)
void scan2_kernel(int* __restrict__ bsums) {
    __shared__ int sd[256];
    const int tid = threadIdx.x;
    const int v = (tid < NBLK) ? bsums[tid] : 0;
    sd[tid] = v;
    __syncthreads();
#pragma unroll
    for (int off = 1; off < 256; off <<= 1) {
        const int t = (tid >= off) ? sd[tid - off] : 0;
        __syncthreads();
        sd[tid] += t;
        __syncthreads();
    }
    if (tid < NBLK) bsums[tid] = sd[tid] - v;
}

__global__ __launch_bounds__(256)
void scan3_kernel(const int* __restrict__ bsums, int* __restrict__ row_ptr,
                  int* __restrict__ cursor) {
    const int idx = blockIdx.x * 256 + threadIdx.x;
    if (idx < NATOMS) {
        const int r = row_ptr[idx] + bsums[blockIdx.x];
        row_ptr[idx] = r;
        cursor[idx]  = r;
    }
    if (idx == 0) row_ptr[NATOMS] = E_TOTAL;
}

__global__ __launch_bounds__(256)
void scatter_kernel(const int* __restrict__ idnb, int* __restrict__ cursor,
                    int* __restrict__ eidx, int* __restrict__ aidxs) {
    const int e = blockIdx.x * 256 + threadIdx.x;
    if (e < E_TOTAL) {
        const int a = idnb[e];
        const int p = atomicAdd(&cursor[a], 1);
        eidx[p]  = e;
        aidxs[p] = a;
    }
}

// ---------------------------------------------------------------------------
// MFMA edge kernel. Block = 4 waves, owns 16 atoms + all their (sorted) edges.
// Per 64-edge tile:
//   h = silu(x @ Wx + bx)  via split-f16 MFMA (hi*hi + hi*lo + lo*hi)
//   g = silu((ca*rbf) @ Wr + br)  same, K=16 zero-padded to 32
//   conv = sc*g*h, run-merged, ds_add into 16-row LDS acc; one store per atom.
// Wave w owns cols [32w,32w+32): 8 C-tiles 16x16, K-steps of 32.
// A/B frags use the SAME (lane-quarter,elem)->k bijection, so the HW k-pairing
// cancels; only the verified C/D map (col=lane&15,row=(lane>>4)*4+reg) is used.
// sX is XOR-swizzled ((row&7)<<3 on f16 idx) -> conflict-free ds_read_b128.
// x/rbf prefetched to regs during previous tile's MFMA (T14).
// ---------------------------------------------------------------------------
__global__ __launch_bounds__(256, 2)
void edge_kernel(const float* __restrict__ x,
                 const float* __restrict__ rbf,
                 const int*   __restrict__ eidx,
                 const int*   __restrict__ aidxs,
                 const int*   __restrict__ row_ptr,
                 const float* __restrict__ Wx,
                 const float* __restrict__ bx,
                 const float* __restrict__ Wr,
                 const float* __restrict__ br,
                 const float* __restrict__ c_a,
                 const float* __restrict__ c_b,
                 const float* __restrict__ c_x,
                 float* __restrict__ acc)
{
    __shared__ _Float16 sXhi[64 * 128];   // 16 KB, swizzled
    __shared__ _Float16 sXlo[64 * 128];   // 16 KB
    __shared__ _Float16 sRhi[64 * 32];    // 4 KB (k>=16 zeroed)
    __shared__ _Float16 sRlo[64 * 32];    // 4 KB
    __shared__ float    sAcc[APB][132];   // 8.4 KB
    __shared__ int      sRel[64];

    const int tid  = threadIdx.x;
    const int w    = tid >> 6;            // wave 0..3
    const int lane = tid & 63;
    const int lq   = lane >> 4;           // quarter-wave 0..3
    const int lm   = lane & 15;

    const int aBase = blockIdx.x * APB;
    const int eBeg  = row_ptr[aBase];
    const int eEnd  = row_ptr[aBase + APB];
    const int nEdge = eEnd - eBeg;
    const int ntile = (nEdge + 63) >> 6;

    const float ca = c_a[0];
    const float sc = c_b[0] * c_x[0];
    const int col0 = w * 32 + lm;
    const int col1 = col0 + 16;
    const float bx0 = bx[col0], bx1 = bx[col1];
    const float br0 = br[col0], br1 = br[col1];

    // ---- hoist W fragments into registers (split f16 hi/lo), once/block ----
    f16x8 wxh[4][2], wxl[4][2];
#pragma unroll
    for (int ks = 0; ks < 4; ++ks)
#pragma unroll
        for (int nt = 0; nt < 2; ++nt) {
            const int n = w * 32 + nt * 16 + lm;
            f16x8 h8, l8;
#pragma unroll
            for (int j = 0; j < 8; ++j) {
                const int k = ks * 32 + lq * 8 + j;
                const float v = Wx[k * EMB + n];
                const _Float16 hv = (_Float16)v;
                h8[j] = hv;
                l8[j] = (_Float16)(v - (float)hv);
            }
            wxh[ks][nt] = h8;
            wxl[ks][nt] = l8;
        }
    f16x8 wrh[2], wrl[2];
#pragma unroll
    for (int nt = 0; nt < 2; ++nt) {
        const int n = w * 32 + nt * 16 + lm;
        f16x8 h8, l8;
#pragma unroll
        for (int j = 0; j < 8; ++j) {
            const int k = lq * 8 + j;
            const float v = (k < NRBF) ? Wr[k * EMB + n] : 0.f;
            const _Float16 hv = (_Float16)v;
            h8[j] = hv;
            l8[j] = (_Float16)(v - (float)hv);
        }
        wrh[nt] = h8;
        wrl[nt] = l8;
    }

    // zero LDS accumulator + the k>=16 region of the rbf tiles (NaN safety)
    for (int f = tid; f < APB * 132; f += 256) ((float*)sAcc)[f] = 0.f;
    for (int f = tid; f < 64 * 16; f += 256) {
        const int idx = (f >> 4) * 32 + 16 + (f & 15);
        sRhi[idx] = (_Float16)0.f;
        sRlo[idx] = (_Float16)0.f;
    }

    float4 px[8];
    float4 pr;
    int    prel = -1;

    auto prefetch = [&](int t) {
        const int base = eBeg + t * 64;
        const int n = min(64, eEnd - base);
#pragma unroll
        for (int i = 0; i < 8; ++i) {
            const int e = (tid >> 5) + i * 8;
            if (e < n) {
                const int eid = eidx[base + e];
                px[i] = *(const float4*)(x + (size_t)eid * EMB + (tid & 31) * 4);
            }
        }
        {
            const int er = tid >> 2;
            if (er < n) {
                const int eid = eidx[base + er];
                pr = *(const float4*)(rbf + (size_t)eid * NRBF + (tid & 3) * 4);
            }
        }
        if (tid < 64) prel = (tid < n) ? (aidxs[base + tid] - aBase) : -1;
    };

    auto write_lds = [&](int pn) {
#pragma unroll
        for (int i = 0; i < 8; ++i) {
            const int e = (tid >> 5) + i * 8;
            if (e < pn) {
                const int kb = (tid & 31) * 4;
                const int idx = (e * 128 + kb) ^ ((e & 7) << 3);
                const float vx[4] = {px[i].x, px[i].y, px[i].z, px[i].w};
                f16x4 h4, l4;
#pragma unroll
                for (int q = 0; q < 4; ++q) {
                    const _Float16 hv = (_Float16)vx[q];
                    h4[q] = hv;
                    l4[q] = (_Float16)(vx[q] - (float)hv);
                }
                *(f16x4*)&sXhi[idx] = h4;
                *(f16x4*)&sXlo[idx] = l4;
            }
        }
        {
            const int er = tid >> 2;
            if (er < pn) {
                const int kb = (tid & 3) * 4;
                const int idx = er * 32 + kb;
                const float vr[4] = {pr.x * ca, pr.y * ca, pr.z * ca, pr.w * ca};
                f16x4 h4, l4;
#pragma unroll
                for (int q = 0; q < 4; ++q) {
                    const _Float16 hv = (_Float16)vr[q];
                    h4[q] = hv;
                    l4[q] = (_Float16)(vr[q] - (float)hv);
                }
                *(f16x4*)&sRhi[idx] = h4;
                *(f16x4*)&sRlo[idx] = l4;
            }
        }
        if (tid < 64) sRel[tid] = prel;
    };

    if (ntile > 0) prefetch(0);

    for (int t = 0; t < ntile; ++t) {
        const int pn = min(64, nEdge - t * 64);
        __syncthreads();              // prev tile's LDS readers done
        write_lds(pn);
        __syncthreads();              // tile t visible
        if (t + 1 < ntile) prefetch(t + 1);   // overlaps MFMA below (T14)

        f32x4 hac[4][2], gac[4][2];
#pragma unroll
        for (int mt = 0; mt < 4; ++mt)
#pragma unroll
            for (int nt = 0; nt < 2; ++nt) {
                hac[mt][nt] = 0.f;
                gac[mt][nt] = 0.f;
            }

#pragma unroll
        for (int mt = 0; mt < 4; ++mt) {
            const int m = mt * 16 + lm;
            {
                const int ridx = m * 32 + lq * 8;
                const f16x8 rh = *(const f16x8*)&sRhi[ridx];
                const f16x8 rl = *(const f16x8*)&sRlo[ridx];
#pragma unroll
                for (int nt = 0; nt < 2; ++nt) {
                    gac[mt][nt] = __builtin_amdgcn_mfma_f32_16x16x32_f16(rh, wrh[nt], gac[mt][nt], 0, 0, 0);
                    gac[mt][nt] = __builtin_amdgcn_mfma_f32_16x16x32_f16(rh, wrl[nt], gac[mt][nt], 0, 0, 0);
                    gac[mt][nt] = __builtin_amdgcn_mfma_f32_16x16x32_f16(rl, wrh[nt], gac[mt][nt], 0, 0, 0);
                }
            }
#pragma unroll
            for (int ks = 0; ks < 4; ++ks) {
                const int xi = (m * 128 + ks * 32 + lq * 8) ^ ((m & 7) << 3);
                const f16x8 xh = *(const f16x8*)&sXhi[xi];
                const f16x8 xl = *(const f16x8*)&sXlo[xi];
#pragma unroll
                for (int nt = 0; nt < 2; ++nt) {
                    hac[mt][nt] = __builtin_amdgcn_mfma_f32_16x16x32_f16(xh, wxh[ks][nt], hac[mt][nt], 0, 0, 0);
                    hac[mt][nt] = __builtin_amdgcn_mfma_f32_16x16x32_f16(xh, wxl[ks][nt], hac[mt][nt], 0, 0, 0);
                    hac[mt][nt] = __builtin_amdgcn_mfma_f32_16x16x32_f16(xl, wxh[ks][nt], hac[mt][nt], 0, 0, 0);
                }
            }
        }

        // ---- epilogue: gate, run-merge 4 consecutive edges, ds_add ----
#pragma unroll
        for (int mt = 0; mt < 4; ++mt) {
            const int embase = mt * 16 + lq * 4;   // C row = lq*4 + reg (m89)
            int rels[4];
#pragma unroll
            for (int r = 0; r < 4; ++r) rels[r] = sRel[embase + r];
            float v0[4], v1[4];
#pragma unroll
            for (int r = 0; r < 4; ++r) {
                const float h0 = silu_f(hac[mt][0][r] + bx0);
                const float g0 = silu_f(gac[mt][0][r] + br0);
                v0[r] = sc * g0 * h0;
                const float h1 = silu_f(hac[mt][1][r] + bx1);
                const float g1 = silu_f(gac[mt][1][r] + br1);
                v1[r] = sc * g1 * h1;
            }
            int cur = rels[0];
            float a0v = v0[0], a1v = v1[0];
#pragma unroll
            for (int r = 1; r < 4; ++r) {
                if (rels[r] == cur) {
                    a0v += v0[r];
                    a1v += v1[r];
                } else {
                    if (cur >= 0) {
                        atomicAdd(&sAcc[cur][col0], a0v);
                        atomicAdd(&sAcc[cur][col1], a1v);
                    }
                    cur = rels[r];
                    a0v = v0[r];
                    a1v = v1[r];
                }
            }
            if (cur >= 0) {
                atomicAdd(&sAcc[cur][col0], a0v);
                atomicAdd(&sAcc[cur][col1], a1v);
            }
        }
    }

    // ---- write 16 owned atom rows exactly once ----
    __syncthreads();
    {
        const int r = tid >> 4;
        const int c = (tid & 15) * 8;
        float* dst = acc + (size_t)(aBase + r) * EMB + c;
        *(float4*)(dst)     = *(const float4*)&sAcc[r][c];
        *(float4*)(dst + 4) = *(const float4*)&sAcc[r][c + 4];
    }
}

// ---------------------------------------------------------------------------
// Atom MLP layer: Y = silu(X @ W + b)
// ---------------------------------------------------------------------------
__global__ __launch_bounds__(256, 2)
void layer_kernel(const float* __restrict__ X,
                  const float* __restrict__ W,
                  const float* __restrict__ b,
                  float* __restrict__ Y,
                  int M)
{
    __shared__ float sX[64][132];

    const int tid = threadIdx.x;
    const int tx  = tid & 15;
    const int ty  = tid >> 4;
    const int j0  = tx * 8;
    const int e0  = ty * 4;

    float brr[8];
#pragma unroll
    for (int c = 0; c < 8; ++c) brr[c] = b[j0 + c];

    const int base = blockIdx.x * 64;
#pragma unroll
    for (int i = 0; i < 8; ++i) {
        const int f = tid + i * 256;
        const int e = f >> 5, seg = f & 31;
        const int row = base + e;
        float4 v = make_float4(0.f, 0.f, 0.f, 0.f);
        if (row < M) v = *(const float4*)(X + (size_t)row * EMB + seg * 4);
        *(float4*)&sX[e][seg * 4] = v;
    }
    __syncthreads();

    float acc[4][8];
#pragma unroll
    for (int i = 0; i < 4; ++i)
#pragma unroll
        for (int c = 0; c < 8; ++c) acc[i][c] = 0.f;

#pragma unroll 2
    for (int kq = 0; kq < EMB / 4; ++kq) {
        const int k = kq * 4;
        float xa[4][4];
#pragma unroll
        for (int i = 0; i < 4; ++i) {
            const float4 v = *(const float4*)&sX[e0 + i][k];
            xa[i][0] = v.x; xa[i][1] = v.y; xa[i][2] = v.z; xa[i][3] = v.w;
        }
#pragma unroll
        for (int kk = 0; kk < 4; ++kk) {
            const float4 w0 = *(const float4*)(W + (size_t)(k + kk) * EMB + j0);
            const float4 w1 = *(const float4*)(W + (size_t)(k + kk) * EMB + j0 + 4);
            const float wv[8] = {w0.x, w0.y, w0.z, w0.w, w1.x, w1.y, w1.z, w1.w};
#pragma unroll
            for (int i = 0; i < 4; ++i) {
                const float xv = xa[i][kk];
#pragma unroll
                for (int c = 0; c < 8; ++c)
                    acc[i][c] = __builtin_fmaf(xv, wv[c], acc[i][c]);
            }
        }
    }

#pragma unroll
    for (int i = 0; i < 4; ++i) {
        const int row = base + e0 + i;
        if (row < M) {
            float o[8];
#pragma unroll
            for (int c = 0; c < 8; ++c) o[c] = silu_f(acc[i][c] + brr[c]);
            float4 v0 = make_float4(o[0], o[1], o[2], o[3]);
            float4 v1 = make_float4(o[4], o[5], o[6], o[7]);
            *(float4*)(Y + (size_t)row * EMB + j0)     = v0;
            *(float4*)(Y + (size_t)row * EMB + j0 + 4) = v1;
        }
    }
}

// ---------------------------------------------------------------------------
// Final projection: out[i] = dot(A[i], Wf) * cf
// ---------------------------------------------------------------------------
__global__ __launch_bounds__(256)
void final_kernel(const float* __restrict__ A,
                  const float* __restrict__ Wf,
                  const float* __restrict__ cf,
                  float* __restrict__ out)
{
    const int i = blockIdx.x * blockDim.x + threadIdx.x;
    if (i >= NATOMS) return;
    const float4* row = (const float4*)(A + (size_t)i * EMB);
    const float4* w   = (const float4*)Wf;
    float acc = 0.f;
#pragma unroll
    for (int k = 0; k < EMB / 4; ++k) {
        const float4 a = row[k];
        const float4 b = w[k];
        acc = __builtin_fmaf(a.x, b.x, acc);
        acc = __builtin_fmaf(a.y, b.y, acc);
        acc = __builtin_fmaf(a.z, b.z, acc);
        acc = __builtin_fmaf(a.w, b.w, acc);
    }
    out[i] = acc * cf[0];
}

extern "C" void kernel_launch(void* const* d_in, const int* in_sizes, int n_in,
                              void* d_out, int out_size, void* d_ws, size_t ws_size,
                              hipStream_t stream) {
    const float* x    = (const float*)d_in[0];
    const float* rbf  = (const float*)d_in[1];
    const int*   idnb = (const int*)  d_in[2];
    // d_in[3] = n_atoms (fixed 50000)
    const float* Wx   = (const float*)d_in[4];
    const float* bx   = (const float*)d_in[5];
    const float* Wr   = (const float*)d_in[6];
    const float* brf  = (const float*)d_in[7];
    const float* W1   = (const float*)d_in[8];
    const float* b1   = (const float*)d_in[9];
    const float* W2   = (const float*)d_in[10];
    const float* b2   = (const float*)d_in[11];
    const float* W3   = (const float*)d_in[12];
    const float* b3   = (const float*)d_in[13];
    const float* Wf   = (const float*)d_in[14];
    const float* c_a  = (const float*)d_in[15];
    const float* c_b  = (const float*)d_in[16];
    const float* c_x  = (const float*)d_in[17];
    const float* c_f  = (const float*)d_in[18];

    float* out = (float*)d_out;
    float* acc = (float*)d_ws;                        // [NATOMS][128] floats
    float* buf = acc + (size_t)NATOMS * EMB;          // [NATOMS][128] floats
    // CSR scratch overlaps buf: dead once edge_kernel completes; buf is first
    // written by layer 1 (stream-ordered after edge_kernel).
    int* eidx    = (int*)buf;                         // 1M
    int* aidxs   = eidx + E_TOTAL;                    // 1M
    int* counts  = aidxs + E_TOTAL;                   // NATOMS
    int* row_ptr = counts + NATOMS;                   // NATOMS+1
    int* cursor  = row_ptr + NATOMS + 1;              // NATOMS
    int* bsums   = cursor + NATOMS;                   // NBLK

    hipMemsetAsync(counts, 0, NATOMS * sizeof(int), stream);

    hist_kernel<<<(E_TOTAL + 255) / 256, 256, 0, stream>>>(idnb, counts);
    scan1_kernel<<<NBLK, 256, 0, stream>>>(counts, row_ptr, bsums);
    scan2_kernel<<<1, 256, 0, stream>>>(bsums);
    scan3_kernel<<<NBLK, 256, 0, stream>>>(bsums, row_ptr, cursor);
    scatter_kernel<<<(E_TOTAL + 255) / 256, 256, 0, stream>>>(idnb, cursor, eidx, aidxs);

    edge_kernel<<<NATOMS / APB, 256, 0, stream>>>(x, rbf, eidx, aidxs, row_ptr,
                                                  Wx, bx, Wr, brf,
                                                  c_a, c_b, c_x, acc);

    const int atiles = (NATOMS + 63) / 64;            // 782
    layer_kernel<<<atiles, 256, 0, stream>>>(acc, W1, b1, buf, NATOMS);
    layer_kernel<<<atiles, 256, 0, stream>>>(buf, W2, b2, acc, NATOMS);
    layer_kernel<<<atiles, 256, 0, stream>>>(acc, W3, b3, buf, NATOMS);

    final_kernel<<<(NATOMS + 255) / 256, 256, 0, stream>>>(buf, Wf, c_f, out);
}

// Round 7
// 512.471 us; speedup vs baseline: 7.4102x; 1.4807x over previous
//
#include <hip/hip_runtime.h>

#define E_TOTAL 1000000
#define EMB     128
#define NRBF    16
#define NATOMS  50000
#define APB     16                         // atoms per block (50000 = 3125*16)
#define NBLK    ((NATOMS + 255) / 256)     // scan blocks

typedef _Float16 f16x8 __attribute__((ext_vector_type(8)));
typedef _Float16 f16x4 __attribute__((ext_vector_type(4)));
typedef float    f32x4 __attribute__((ext_vector_type(4)));

__device__ __forceinline__ float silu_f(float v) {
    return v * (1.0f / (1.0f + __expf(-v)));
}

// ---------------------------------------------------------------------------
// CSR build: counting sort of edge ids by destination atom.
// ---------------------------------------------------------------------------
__global__ __launch_bounds__(256)
void hist_kernel(const int* __restrict__ idnb, int* __restrict__ counts) {
    const int e = blockIdx.x * 256 + threadIdx.x;
    if (e < E_TOTAL) atomicAdd(&counts[idnb[e]], 1);
}

__global__ __launch_bounds__(256)
void scan1_kernel(const int* __restrict__ counts, int* __restrict__ row_ptr,
                  int* __restrict__ bsums) {
    __shared__ int sd[256];
    const int tid = threadIdx.x;
    const int idx = blockIdx.x * 256 + tid;
    const int v = (idx < NATOMS) ? counts[idx] : 0;
    sd[tid] = v;
    __syncthreads();
#pragma unroll
    for (int off = 1; off < 256; off <<= 1) {
        const int t = (tid >= off) ? sd[tid - off] : 0;
        __syncthreads();
        sd[tid] += t;
        __syncthreads();
    }
    if (idx < NATOMS) row_ptr[idx] = sd[tid] - v;
    if (tid == 255) bsums[blockIdx.x] = sd[255];
}

__global__ __launch_bounds__(256)
void scan2_kernel(int* __restrict__ bsums) {
    __shared__ int sd[256];
    const int tid = threadIdx.x;
    const int v = (tid < NBLK) ? bsums[tid] : 0;
    sd[tid] = v;
    __syncthreads();
#pragma unroll
    for (int off = 1; off < 256; off <<= 1) {
        const int t = (tid >= off) ? sd[tid - off] : 0;
        __syncthreads();
        sd[tid] += t;
        __syncthreads();
    }
    if (tid < NBLK) bsums[tid] = sd[tid] - v;
}

__global__ __launch_bounds__(256)
void scan3_kernel(const int* __restrict__ bsums, int* __restrict__ row_ptr,
                  int* __restrict__ cursor) {
    const int idx = blockIdx.x * 256 + threadIdx.x;
    if (idx < NATOMS) {
        const int r = row_ptr[idx] + bsums[blockIdx.x];
        row_ptr[idx] = r;
        cursor[idx]  = r;
    }
    if (idx == 0) row_ptr[NATOMS] = E_TOTAL;
}

__global__ __launch_bounds__(256)
void scatter_kernel(const int* __restrict__ idnb, int* __restrict__ cursor,
                    int* __restrict__ eidx, int* __restrict__ aidxs) {
    const int e = blockIdx.x * 256 + threadIdx.x;
    if (e < E_TOTAL) {
        const int a = idnb[e];
        const int p = atomicAdd(&cursor[a], 1);
        eidx[p]  = e;
        aidxs[p] = a;
    }
}

// ---------------------------------------------------------------------------
// MFMA edge kernel (round-4 proven structure; single-f16 x/rbf, split-f16 W).
// Block = 4 waves, owns 16 atoms + their sorted edges. Per 64-edge tile:
//   prefetch regs (t+1 issued before compute of t) -> cvt-once-at-write f16
//   LDS (XOR swizzle on 8-f16 groups) -> 80 MFMA -> gate -> run-merge ->
//   LDS-atomic 16-row acc; one plain store per owned atom row at the end.
// ---------------------------------------------------------------------------
__global__ __launch_bounds__(256, 2)
void edge_kernel(const float* __restrict__ x,
                 const float* __restrict__ rbf,
                 const int*   __restrict__ eidx,
                 const int*   __restrict__ aidxs,
                 const int*   __restrict__ row_ptr,
                 const float* __restrict__ Wx,
                 const float* __restrict__ bx,
                 const float* __restrict__ Wr,
                 const float* __restrict__ br,
                 const float* __restrict__ c_a,
                 const float* __restrict__ c_b,
                 const float* __restrict__ c_x,
                 float* __restrict__ acc)
{
    __shared__ _Float16 sX[64 * 128];   // 16 KB, XOR-swizzled 8-f16 groups
    __shared__ _Float16 sR[64 * 40];    // 5 KB, stride-40 pad (bank-friendly), k>=16 zero
    __shared__ float    sAcc[APB][132]; // 8.4 KB
    __shared__ int      sAid[64];

    const int tid  = threadIdx.x;
    const int w    = tid >> 6;
    const int lane = tid & 63;
    const int lq   = lane >> 4;
    const int lm   = lane & 15;

    const int aBase = blockIdx.x * APB;
    const int eBeg  = row_ptr[aBase];
    const int eEnd  = row_ptr[aBase + APB];
    const int nEdge = eEnd - eBeg;
    const int ntile = (nEdge + 63) >> 6;

    const float ca = c_a[0];
    const float sc = c_b[0] * c_x[0];
    const int col0 = w * 32 + lm;
    const int col1 = col0 + 16;
    const float bx0 = bx[col0], bx1 = bx[col1];
    const float br0 = br[col0], br1 = br[col1];

    // ---- hoist split-W fragments from global, once per block (proven) ----
    f16x8 wxh[4][2], wxl[4][2], wrh[2], wrl[2];
#pragma unroll
    for (int ks = 0; ks < 4; ++ks)
#pragma unroll
        for (int nt = 0; nt < 2; ++nt) {
            const int n = w * 32 + nt * 16 + lm;
            f16x8 h8, l8;
#pragma unroll
            for (int j = 0; j < 8; ++j) {
                const int k = ks * 32 + lq * 8 + j;
                const float v = Wx[k * EMB + n];
                const _Float16 hv = (_Float16)v;
                h8[j] = hv;
                l8[j] = (_Float16)(v - (float)hv);
            }
            wxh[ks][nt] = h8;
            wxl[ks][nt] = l8;
        }
#pragma unroll
    for (int nt = 0; nt < 2; ++nt) {
        const int n = w * 32 + nt * 16 + lm;
        f16x8 h8, l8;
#pragma unroll
        for (int j = 0; j < 8; ++j) {
            const int k = lq * 8 + j;
            const float v = (k < NRBF) ? Wr[k * EMB + n] : 0.f;
            const _Float16 hv = (_Float16)v;
            h8[j] = hv;
            l8[j] = (_Float16)(v - (float)hv);
        }
        wrh[nt] = h8;
        wrl[nt] = l8;
    }

    // init LDS: zero accumulator; zero sR k in [16,40)
    for (int f = tid; f < APB * 132; f += 256) ((float*)sAcc)[f] = 0.f;
    for (int f = tid; f < 64 * 24; f += 256)
        sR[(f / 24) * 40 + 16 + (f % 24)] = (_Float16)0.f;

    float4 px[8];
    float4 pr;
    int    prel = -1;

    auto prefetch = [&](int t) {
        const int nb = eBeg + t * 64;
#pragma unroll
        for (int i = 0; i < 8; ++i) {
            const int e = (tid >> 5) + i * 8;
            const int eid = eidx[min(nb + e, eEnd - 1)];
            px[i] = *(const float4*)(x + (size_t)eid * EMB + (tid & 31) * 4);
        }
        {
            const int er = tid >> 2;
            const int eid = eidx[min(nb + er, eEnd - 1)];
            pr = *(const float4*)(rbf + (size_t)eid * NRBF + (tid & 3) * 4);
        }
        if (tid < 64) prel = (nb + tid < eEnd) ? (aidxs[nb + tid] - aBase) : -1;
    };

    auto write_lds = [&]() {
#pragma unroll
        for (int i = 0; i < 8; ++i) {
            const int e = (tid >> 5) + i * 8;
            const int kb = (tid & 31) * 4;
            const int idx = (e * 128 + kb) ^ ((e & 7) << 3);
            f16x4 h4 = {(_Float16)px[i].x, (_Float16)px[i].y,
                        (_Float16)px[i].z, (_Float16)px[i].w};
            *(f16x4*)&sX[idx] = h4;
        }
        {
            const int er = tid >> 2;
            const int kb = (tid & 3) * 4;
            f16x4 r4 = {(_Float16)(pr.x * ca), (_Float16)(pr.y * ca),
                        (_Float16)(pr.z * ca), (_Float16)(pr.w * ca)};
            *(f16x4*)&sR[er * 40 + kb] = r4;
        }
        if (tid < 64) sAid[tid] = prel;
    };

    if (ntile > 0) prefetch(0);

    for (int t = 0; t < ntile; ++t) {
        __syncthreads();                 // prev tile's readers (or init) done
        write_lds();
        __syncthreads();                 // tile t visible
        if (t + 1 < ntile) prefetch(t + 1);   // issue early, consumed next iter

        // mth-halved accumulation to cap register pressure
#pragma unroll
        for (int mth = 0; mth < 2; ++mth) {
            f32x4 hac[2][2], gac[2][2];
#pragma unroll
            for (int mi = 0; mi < 2; ++mi)
#pragma unroll
                for (int nt = 0; nt < 2; ++nt) { hac[mi][nt] = 0.f; gac[mi][nt] = 0.f; }

#pragma unroll
            for (int mi = 0; mi < 2; ++mi) {
                const int m = (mth * 2 + mi) * 16 + lm;
                // g: K=32 (k>=16 zero on both operands)
                const f16x8 rh = *(const f16x8*)&sR[m * 40 + lq * 8];
#pragma unroll
                for (int nt = 0; nt < 2; ++nt) {
                    gac[mi][nt] = __builtin_amdgcn_mfma_f32_16x16x32_f16(rh, wrh[nt], gac[mi][nt], 0, 0, 0);
                    gac[mi][nt] = __builtin_amdgcn_mfma_f32_16x16x32_f16(rh, wrl[nt], gac[mi][nt], 0, 0, 0);
                }
                // h: K=128 in 4 steps, 2 MFMA per step (x_f16 * (Wh, Wl))
#pragma unroll
                for (int ks = 0; ks < 4; ++ks) {
                    const int xi = (m * 128 + ks * 32 + lq * 8) ^ ((m & 7) << 3);
                    const f16x8 xh = *(const f16x8*)&sX[xi];
#pragma unroll
                    for (int nt = 0; nt < 2; ++nt) {
                        hac[mi][nt] = __builtin_amdgcn_mfma_f32_16x16x32_f16(xh, wxh[ks][nt], hac[mi][nt], 0, 0, 0);
                        hac[mi][nt] = __builtin_amdgcn_mfma_f32_16x16x32_f16(xh, wxl[ks][nt], hac[mi][nt], 0, 0, 0);
                    }
                }
            }

            // ---- epilogue: gate, run-merge 4 consecutive sorted edges, ds_add ----
#pragma unroll
            for (int mi = 0; mi < 2; ++mi) {
                const int embase = (mth * 2 + mi) * 16 + lq * 4;  // C row = lq*4+reg
                int rels[4];
#pragma unroll
                for (int r = 0; r < 4; ++r) rels[r] = sAid[embase + r];
                float v0[4], v1[4];
#pragma unroll
                for (int r = 0; r < 4; ++r) {
                    v0[r] = sc * silu_f(gac[mi][0][r] + br0) * silu_f(hac[mi][0][r] + bx0);
                    v1[r] = sc * silu_f(gac[mi][1][r] + br1) * silu_f(hac[mi][1][r] + bx1);
                }
                int cur = rels[0];
                float a0v = v0[0], a1v = v1[0];
#pragma unroll
                for (int r = 1; r < 4; ++r) {
                    if (rels[r] == cur) {
                        a0v += v0[r]; a1v += v1[r];
                    } else {
                        if (cur >= 0) {
                            atomicAdd(&sAcc[cur][col0], a0v);
                            atomicAdd(&sAcc[cur][col1], a1v);
                        }
                        cur = rels[r]; a0v = v0[r]; a1v = v1[r];
                    }
                }
                if (cur >= 0) {
                    atomicAdd(&sAcc[cur][col0], a0v);
                    atomicAdd(&sAcc[cur][col1], a1v);
                }
            }
        }
    }

    __syncthreads();   // sAcc atomics (or zero-init) visible
    {
        const int r = tid >> 4;
        const int c = (tid & 15) * 8;
        float* dst = acc + (size_t)(aBase + r) * EMB + c;
        *(float4*)(dst)     = *(const float4*)&sAcc[r][c];
        *(float4*)(dst + 4) = *(const float4*)&sAcc[r][c + 4];
    }
}

// ---------------------------------------------------------------------------
// MFMA atom-MLP layer: Y = silu(X @ W + b). 2 subtiles of 64 rows per block
// (amortizes the per-block W hoist). Same staging/swizzle as edge kernel.
// ---------------------------------------------------------------------------
__global__ __launch_bounds__(256, 2)
void layer_kernel(const float* __restrict__ X,
                  const float* __restrict__ W,
                  const float* __restrict__ b,
                  float* __restrict__ Y, int M)
{
    __shared__ _Float16 sX[64 * 128];

    const int tid  = threadIdx.x;
    const int w    = tid >> 6;
    const int lane = tid & 63;
    const int lq   = lane >> 4;
    const int lm   = lane & 15;

    const int col0 = w * 32 + lm;
    const int col1 = col0 + 16;
    const float b0 = b[col0], b1 = b[col1];

    f16x8 wh[4][2], wl[4][2];
#pragma unroll
    for (int ks = 0; ks < 4; ++ks)
#pragma unroll
        for (int nt = 0; nt < 2; ++nt) {
            const int n = w * 32 + nt * 16 + lm;
            f16x8 h8, l8;
#pragma unroll
            for (int j = 0; j < 8; ++j) {
                const int k = ks * 32 + lq * 8 + j;
                const float v = W[k * EMB + n];
                const _Float16 hv = (_Float16)v;
                h8[j] = hv;
                l8[j] = (_Float16)(v - (float)hv);
            }
            wh[ks][nt] = h8;
            wl[ks][nt] = l8;
        }

#pragma unroll
    for (int sub = 0; sub < 2; ++sub) {
        const int base = blockIdx.x * 128 + sub * 64;
        __syncthreads();               // prev subtile readers done
#pragma unroll
        for (int i = 0; i < 8; ++i) {
            const int e = (tid >> 5) + i * 8;
            const int row = min(base + e, M - 1);
            const float4 v = *(const float4*)(X + (size_t)row * EMB + (tid & 31) * 4);
            const int kb = (tid & 31) * 4;
            const int idx = (e * 128 + kb) ^ ((e & 7) << 3);
            f16x4 h4 = {(_Float16)v.x, (_Float16)v.y, (_Float16)v.z, (_Float16)v.w};
            *(f16x4*)&sX[idx] = h4;
        }
        __syncthreads();

#pragma unroll
        for (int mth = 0; mth < 2; ++mth) {
            f32x4 hac[2][2];
#pragma unroll
            for (int mi = 0; mi < 2; ++mi)
#pragma unroll
                for (int nt = 0; nt < 2; ++nt) hac[mi][nt] = 0.f;

#pragma unroll
            for (int mi = 0; mi < 2; ++mi) {
                const int m = (mth * 2 + mi) * 16 + lm;
#pragma unroll
                for (int ks = 0; ks < 4; ++ks) {
                    const int xi = (m * 128 + ks * 32 + lq * 8) ^ ((m & 7) << 3);
                    const f16x8 xh = *(const f16x8*)&sX[xi];
#pragma unroll
                    for (int nt = 0; nt < 2; ++nt) {
                        hac[mi][nt] = __builtin_amdgcn_mfma_f32_16x16x32_f16(xh, wh[ks][nt], hac[mi][nt], 0, 0, 0);
                        hac[mi][nt] = __builtin_amdgcn_mfma_f32_16x16x32_f16(xh, wl[ks][nt], hac[mi][nt], 0, 0, 0);
                    }
                }
            }
#pragma unroll
            for (int mi = 0; mi < 2; ++mi) {
                const int rb = base + (mth * 2 + mi) * 16 + lq * 4;
#pragma unroll
                for (int r = 0; r < 4; ++r) {
                    const int row = rb + r;
                    if (row < M) {
                        Y[(size_t)row * EMB + col0] = silu_f(hac[mi][0][r] + b0);
                        Y[(size_t)row * EMB + col1] = silu_f(hac[mi][1][r] + b1);
                    }
                }
            }
        }
    }
}

// ---------------------------------------------------------------------------
// Final projection: out[i] = dot(A[i], Wf) * cf
// ---------------------------------------------------------------------------
__global__ __launch_bounds__(256)
void final_kernel(const float* __restrict__ A,
                  const float* __restrict__ Wf,
                  const float* __restrict__ cf,
                  float* __restrict__ out)
{
    const int i = blockIdx.x * blockDim.x + threadIdx.x;
    if (i >= NATOMS) return;
    const float4* row = (const float4*)(A + (size_t)i * EMB);
    const float4* w   = (const float4*)Wf;
    float acc = 0.f;
#pragma unroll
    for (int k = 0; k < EMB / 4; ++k) {
        const float4 a = row[k];
        const float4 b = w[k];
        acc = __builtin_fmaf(a.x, b.x, acc);
        acc = __builtin_fmaf(a.y, b.y, acc);
        acc = __builtin_fmaf(a.z, b.z, acc);
        acc = __builtin_fmaf(a.w, b.w, acc);
    }
    out[i] = acc * cf[0];
}

extern "C" void kernel_launch(void* const* d_in, const int* in_sizes, int n_in,
                              void* d_out, int out_size, void* d_ws, size_t ws_size,
                              hipStream_t stream) {
    const float* x    = (const float*)d_in[0];
    const float* rbf  = (const float*)d_in[1];
    const int*   idnb = (const int*)  d_in[2];
    // d_in[3] = n_atoms (fixed 50000)
    const float* Wx   = (const float*)d_in[4];
    const float* bx   = (const float*)d_in[5];
    const float* Wr   = (const float*)d_in[6];
    const float* brf  = (const float*)d_in[7];
    const float* W1   = (const float*)d_in[8];
    const float* b1   = (const float*)d_in[9];
    const float* W2   = (const float*)d_in[10];
    const float* b2   = (const float*)d_in[11];
    const float* W3   = (const float*)d_in[12];
    const float* b3   = (const float*)d_in[13];
    const float* Wf   = (const float*)d_in[14];
    const float* c_a  = (const float*)d_in[15];
    const float* c_b  = (const float*)d_in[16];
    const float* c_x  = (const float*)d_in[17];
    const float* c_f  = (const float*)d_in[18];

    float* out = (float*)d_out;
    float* acc = (float*)d_ws;                        // [NATOMS][128] f32
    float* buf = acc + (size_t)NATOMS * EMB;          // [NATOMS][128] f32
    // CSR scratch inside buf (dead before layer 1 writes buf)
    int* eidx    = (int*)buf;                         // 1M
    int* aidxs   = eidx + E_TOTAL;                    // 1M
    int* counts  = aidxs + E_TOTAL;                   // NATOMS
    int* row_ptr = counts + NATOMS;                   // NATOMS+1
    int* cursor  = row_ptr + NATOMS + 1;              // NATOMS
    int* bsums   = cursor + NATOMS;                   // NBLK

    hipMemsetAsync(counts, 0, NATOMS * sizeof(int), stream);

    hist_kernel<<<(E_TOTAL + 255) / 256, 256, 0, stream>>>(idnb, counts);
    scan1_kernel<<<NBLK, 256, 0, stream>>>(counts, row_ptr, bsums);
    scan2_kernel<<<1, 256, 0, stream>>>(bsums);
    scan3_kernel<<<NBLK, 256, 0, stream>>>(bsums, row_ptr, cursor);
    scatter_kernel<<<(E_TOTAL + 255) / 256, 256, 0, stream>>>(idnb, cursor, eidx, aidxs);

    edge_kernel<<<NATOMS / APB, 256, 0, stream>>>(x, rbf, eidx, aidxs, row_ptr,
                                                  Wx, bx, Wr, brf,
                                                  c_a, c_b, c_x, acc);

    const int ltiles = (NATOMS + 127) / 128;          // 391
    layer_kernel<<<ltiles, 256, 0, stream>>>(acc, W1, b1, buf, NATOMS);
    layer_kernel<<<ltiles, 256, 0, stream>>>(buf, W2, b2, acc, NATOMS);
    layer_kernel<<<ltiles, 256, 0, stream>>>(acc, W3, b3, buf, NATOMS);

    final_kernel<<<(NATOMS + 255) / 256, 256, 0, stream>>>(buf, Wf, c_f, out);
}